// Round 5
// baseline (1131.486 us; speedup 1.0000x reference)
//
#include <hip/hip_runtime.h>

typedef __attribute__((ext_vector_type(8))) short s8b;       // 8 x bf16
typedef __attribute__((ext_vector_type(16))) float v16f;     // 32x32 f32 acc
typedef __attribute__((ext_vector_type(4)))  float v4f;
typedef __attribute__((ext_vector_type(4)))  unsigned int u32x4;
typedef __attribute__((ext_vector_type(4)))  int i32x4;      // 16 x i8 operand
typedef __attribute__((ext_vector_type(16))) int i32x16;     // 32x32 i32 acc
typedef unsigned short u16;
typedef unsigned int u32;

__device__ __forceinline__ float clamp01(float v) {
  return __builtin_fminf(__builtin_fmaxf(v, 0.0f), 1.0f);
}

__device__ __forceinline__ void split1(float f, u16 &h, u16 &l) {
  unsigned u = __builtin_bit_cast(unsigned, f);
  unsigned hu = u & 0xffff0000u;
  float lf = f - __builtin_bit_cast(float, hu);
  h = (u16)(u >> 16);
  l = (u16)(__builtin_bit_cast(unsigned, lf) >> 16);
}

__device__ __forceinline__ v16f mfma32(s8b a, s8b b, v16f c) {
  return __builtin_amdgcn_mfma_f32_32x32x16_bf16(a, b, c, 0, 0, 0);
}
__device__ __forceinline__ i32x16 mfma_i8_32(i32x4 a, i32x4 b, i32x16 c) {
  return __builtin_amdgcn_mfma_i32_32x32x32_i8(a, b, c, 0, 0, 0);
}
__device__ __forceinline__ i32x4 mfma_i8_16(i32x4 a, i32x4 b, i32x4 c) {
  return __builtin_amdgcn_mfma_i32_16x16x64_i8(a, b, c, 0, 0, 0);
}

// state Q14: packed u16 = h (0..64, low byte) | l (signed, high byte)
__device__ __forceinline__ u16 enc_q(float v) {
  int q = (int)rintf(v * 16384.0f);
  int h = (q + 128) >> 8;
  int lo = q - (h << 8);
  return (u16)((h & 0xff) | ((lo & 0xff) << 8));
}

// unpack 16 packed u16 -> h-frag / l-frag (i8x16 each) via v_perm
__device__ __forceinline__ void unpack_hl(u32x4 A, u32x4 B, i32x4 &h, i32x4 &l) {
  const unsigned SH = 0x06040200u, SL = 0x07050301u;
  h.x = (int)__builtin_amdgcn_perm(A.y, A.x, SH);
  h.y = (int)__builtin_amdgcn_perm(A.w, A.z, SH);
  h.z = (int)__builtin_amdgcn_perm(B.y, B.x, SH);
  h.w = (int)__builtin_amdgcn_perm(B.w, B.z, SH);
  l.x = (int)__builtin_amdgcn_perm(A.y, A.x, SL);
  l.y = (int)__builtin_amdgcn_perm(A.w, A.z, SL);
  l.z = (int)__builtin_amdgcn_perm(B.y, B.x, SL);
  l.w = (int)__builtin_amdgcn_perm(B.w, B.z, SL);
}

// swizzled u16 index in a [32][256] state tile: 16B chunk c=col>>3 -> c^(row&7)
__device__ __forceinline__ int sw_idx(int row, int col) {
  return row * 256 + ((((col >> 3) ^ (row & 7))) << 3) + (col & 7);
}

// ---------------- prep kernels ----------------------------------------------
// W2/W3/W0 -> single i8 Q11 (|W| <= 1/16 so Q11 fits i8); W4 -> bf16 h/l
__global__ void k_prep_w(const float* __restrict__ W2, const float* __restrict__ W3,
                         const float* __restrict__ W4, const float* __restrict__ W0,
                         signed char* __restrict__ w2q, signed char* __restrict__ w3q,
                         signed char* __restrict__ w0q,
                         u16* __restrict__ w4h, u16* __restrict__ w4l) {
  int i = blockIdx.x * 256 + threadIdx.x;
  if (i < 65536) {
    int q = (int)rintf(W2[i] * 2048.0f);
    q = min(max(q, -127), 127); w2q[i] = (signed char)q;
    q = (int)rintf(W3[i] * 2048.0f);
    q = min(max(q, -127), 127); w3q[i] = (signed char)q;
  }
  if (i < 4096) {                           // W0 padded [16][256]
    int n = i >> 8, k = i & 255;
    float v = (n < 10) ? W0[n * 256 + k] : 0.0f;
    int q = (int)rintf(v * 2048.0f);
    q = min(max(q, -127), 127); w0q[i] = (signed char)q;
  }
  if (i < 200704) {
    u16 h, lo;
    split1(W4[i], h, lo); w4h[i] = h; w4l[i] = lo;
  }
}

// W1 padded [256 out][32 k] i8 Q11 (k<10 valid); b0 padded [16]
__global__ void k_prep_small(const float* __restrict__ W1, const float* __restrict__ b0,
                             signed char* __restrict__ w1q, float* __restrict__ b0p) {
  int i = blockIdx.x * 256 + threadIdx.x;
  if (i < 8192) {
    int n = i >> 5, k = i & 31;
    float v = (k < 10) ? W1[n * 10 + k] : 0.0f;
    int q = (int)rintf(v * 2048.0f);
    q = min(max(q, -127), 127); w1q[i] = (signed char)q;
  } else if (i < 8208) {
    int k = i - 8192;
    b0p[k] = (k < 10) ? b0[k] : 0.0f;
  }
}

// ---------------- drive = data @ W4^T + b4 (bf16 3-pass, once) ---------------
__device__ __forceinline__ void split_pack8(v4f x0, v4f x1, s8b &hi, s8b &lo) {
  float f[8];
  #pragma unroll
  for (int j = 0; j < 4; ++j) { f[j] = x0[j]; f[4 + j] = x1[j]; }
  u32x4 vh, vl;
  #pragma unroll
  for (int j = 0; j < 4; ++j) {
    unsigned u0 = __builtin_bit_cast(unsigned, f[2 * j]);
    unsigned u1 = __builtin_bit_cast(unsigned, f[2 * j + 1]);
    unsigned h0 = u0 & 0xffff0000u, h1 = u1 & 0xffff0000u;
    float l0 = f[2 * j]     - __builtin_bit_cast(float, h0);
    float l1 = f[2 * j + 1] - __builtin_bit_cast(float, h1);
    vh[j] = (u0 >> 16) | h1;
    vl[j] = (__builtin_bit_cast(unsigned, l0) >> 16) |
            (__builtin_bit_cast(unsigned, l1) & 0xffff0000u);
  }
  hi = __builtin_bit_cast(s8b, vh);
  lo = __builtin_bit_cast(s8b, vl);
}

__global__ void __launch_bounds__(256, 1) k_drive(
    const float* __restrict__ data, const u16* __restrict__ w4h,
    const u16* __restrict__ w4l, const float* __restrict__ b4,
    float* __restrict__ drive) {
  const int tid = threadIdx.x;
  const int w = tid >> 6, l = tid & 63;
  const int m = l & 31, g = l >> 5;
  const int rb = blockIdx.x * 64;
  const int nbase = w * 64;
  float b4v0 = b4[nbase + m], b4v1 = b4[nbase + 32 + m];
  v16f acc[2][2];
  #pragma unroll
  for (int r = 0; r < 16; ++r) {
    acc[0][0][r] = b4v0; acc[0][1][r] = b4v1;
    acc[1][0][r] = b4v0; acc[1][1][r] = b4v1;
  }
  for (int kt = 0; kt < 49; ++kt) {
    int k0 = kt * 16 + g * 8;
    s8b aH[2], aL[2], bH[2], bL[2];
    #pragma unroll
    for (int mt = 0; mt < 2; ++mt) {
      const float* p = data + (size_t)(rb + 32 * mt + m) * 784 + k0;
      v4f x0 = *(const v4f*)p;
      v4f x1 = *(const v4f*)(p + 4);
      split_pack8(x0, x1, aH[mt], aL[mt]);
    }
    #pragma unroll
    for (int nt = 0; nt < 2; ++nt) {
      int off = (nbase + 32 * nt + m) * 784 + k0;
      bH[nt] = *(const s8b*)(w4h + off);
      bL[nt] = *(const s8b*)(w4l + off);
    }
    #pragma unroll
    for (int mt = 0; mt < 2; ++mt)
      #pragma unroll
      for (int nt = 0; nt < 2; ++nt) {
        acc[mt][nt] = mfma32(aH[mt], bH[nt], acc[mt][nt]);
        acc[mt][nt] = mfma32(aL[mt], bH[nt], acc[mt][nt]);
        acc[mt][nt] = mfma32(aH[mt], bL[nt], acc[mt][nt]);
      }
  }
  #pragma unroll
  for (int mt = 0; mt < 2; ++mt)
    #pragma unroll
    for (int nt = 0; nt < 2; ++nt)
      #pragma unroll
      for (int r = 0; r < 16; ++r) {
        int row = rb + 32 * mt + (r & 3) + 8 * (r >> 2) + 4 * g;
        int col = nbase + 32 * nt + m;
        drive[(size_t)row * 256 + col] = acc[mt][nt][r];
      }
}

// ---------------- main persistent stepper ------------------------------------
// one 32-row m-tile of a K=256 i8 gemm; weights in registers
__device__ __forceinline__ void gemm1(const u16* __restrict__ sP, int m, int g,
    const i32x4* bq, i32x16 &hh, i32x16 &c1) {
  const int rs = (m & 7) << 3;
  const u16* ap = sP + m * 256;
  #pragma unroll
  for (int kt = 0; kt < 8; ++kt) {
    const int s = 2 * kt + g;
    const int i0 = (s << 4) ^ rs;
    u32x4 A0 = *(const u32x4*)(ap + i0);
    u32x4 A1 = *(const u32x4*)(ap + (i0 ^ 8));
    i32x4 ah, al; unpack_hl(A0, A1, ah, al);
    hh = mfma_i8_32(ah, bq[kt], hh);
    c1 = mfma_i8_32(al, bq[kt], c1);
  }
}

#define S0_STRIDE 40   // u16 stride for [32][40] s0 tile (80 B, 16B-aligned rows)

__global__ void __launch_bounds__(512, 4) k_main(
    const float* __restrict__ s0g, const float* __restrict__ s1g,
    const float* __restrict__ s2g, const float* __restrict__ b2,
    const int* __restrict__ Tp,
    const signed char* __restrict__ w2q, const signed char* __restrict__ w3q,
    const signed char* __restrict__ w0q, const signed char* __restrict__ w1q,
    const float* __restrict__ b0p, const float* __restrict__ drive,
    float* __restrict__ out0, float* __restrict__ out1, float* __restrict__ out2) {
  extern __shared__ u16 smem[];
  u16* s1A = smem;                  // [32][256] u16 swizzled (16 KB each)
  u16* s1B = smem + 8192;
  u16* s2A = smem + 16384;
  u16* s2B = smem + 24576;
  u16* s0A = smem + 32768;          // [32][40] u16 packed (2560 B each)
  u16* s0B = smem + 34048;
  signed char* w0s = (signed char*)(smem + 35328);  // [16][256] i8 swizzled, 4 KB
  // total: 70656 + 4096 = 74752 B

  const int tid = threadIdx.x;
  const int w = tid >> 6, l = tid & 63;
  const int m = l & 31, g = l >> 5;
  const int m16 = l & 15, g4 = l >> 4;
  const int rb = blockIdx.x * 32;
  const int col = w * 32 + m;

  // ---- stage weights into registers (once): 68 VGPR ----
  i32x4 w2F[8], w3F[8], w1F;
  {
    const int wo = col * 256 + g * 16;
    #pragma unroll
    for (int kt = 0; kt < 8; ++kt) {
      w2F[kt] = *(const i32x4*)(w2q + wo + kt * 32);
      w3F[kt] = *(const i32x4*)(w3q + wo + kt * 32);
    }
    w1F = *(const i32x4*)(w1q + col * 32 + g * 16);
  }

  // ---- init LDS states ----
  for (int i = tid; i < 8192; i += 512) {
    int row = i >> 8, c = i & 255;
    int idx = sw_idx(row, c);
    s1A[idx] = enc_q(s1g[(size_t)(rb + row) * 256 + c]);
    s2A[idx] = enc_q(s2g[(size_t)(rb + row) * 256 + c]);
  }
  for (int i = tid; i < 32 * S0_STRIDE; i += 512) {
    int row = i / S0_STRIDE, c = i - row * S0_STRIDE;
    float v = (c < 10) ? s0g[(rb + row) * 10 + c] : 0.0f;
    s0A[i] = enc_q(v);
    s0B[i] = enc_q(0.0f);          // pad cols must stay encoded-zero
  }
  if (tid < 256) {                  // stage W0 into LDS, swizzled (16B chunks)
    int r = tid >> 4, c = tid & 15;
    int dst = r * 256 + ((c ^ (r & 7)) << 4);
    *(u32x4*)(w0s + dst) = *(const u32x4*)(w0q + r * 256 + c * 16);
  }

  const float b2v = b2[col];
  const float b0v = b0p[m16];
  const int T = Tp[0];
  const int cq = col >> 3, cw = col & 7;   // write-back chunk/offset
  __syncthreads();

  u16 *s1c = s1A, *s1n = s1B, *s2c = s2A, *s2n = s2B;
  u16 *s0c = s0A, *s0n = s0B;

  for (int t = 0; t < T; ++t) {
    const bool last = (t == T - 1);
    i32x16 hh, c1;

    // ---- n2 = clamp(drive + s1 @ W3^T) ----
    #pragma unroll
    for (int r = 0; r < 16; ++r) { hh[r] = 0; c1[r] = 0; }
    gemm1(s1c, m, g, w3F, hh, c1);
    #pragma unroll
    for (int r = 0; r < 16; ++r) {
      int row = (r & 3) + 8 * (r >> 2) + 4 * g;
      float dv = drive[(size_t)(rb + row) * 256 + col];   // L2-resident
      float v = clamp01(dv + (float)((hh[r] << 8) + c1[r]) * 0x1p-25f);
      s2n[row * 256 + ((cq ^ (row & 7)) << 3) + cw] = enc_q(v);
      if (last) out2[(size_t)(rb + row) * 256 + col] = v;
    }

    // ---- n1 = clamp(b2 + s2 @ W2^T + s0 @ W1^T) ----
    #pragma unroll
    for (int r = 0; r < 16; ++r) { hh[r] = 0; c1[r] = 0; }
    {   // s0 contribution: one K=32 slice (cols 10..31 are zero)
      const u16* ap = s0c + m * S0_STRIDE + g * 16;
      u32x4 A0 = *(const u32x4*)(ap);
      u32x4 A1 = *(const u32x4*)(ap + 8);
      i32x4 ah, al; unpack_hl(A0, A1, ah, al);
      hh = mfma_i8_32(ah, w1F, hh);
      c1 = mfma_i8_32(al, w1F, c1);
    }
    gemm1(s2c, m, g, w2F, hh, c1);
    #pragma unroll
    for (int r = 0; r < 16; ++r) {
      int row = (r & 3) + 8 * (r >> 2) + 4 * g;
      float v = clamp01(b2v + (float)((hh[r] << 8) + c1[r]) * 0x1p-25f);
      s1n[row * 256 + ((cq ^ (row & 7)) << 3) + cw] = enc_q(v);
      if (last) out1[(size_t)(rb + row) * 256 + col] = v;
    }

    // ---- n0 = clamp(b0 + s1 @ W0^T), waves 0-1, 16x16x64 ----
    if (w < 2) {
      const int arow = 16 * w + m16;
      const int rsh = (arow & 7) << 3;
      const u16* ap = s1c + arow * 256;
      i32x4 ph, p1;
      ph.x = ph.y = ph.z = ph.w = 0;
      p1.x = p1.y = p1.z = p1.w = 0;
      #pragma unroll
      for (int kt = 0; kt < 4; ++kt) {
        const int s = kt * 4 + g4;
        const int i0 = (s << 4) ^ rsh;
        u32x4 A0 = *(const u32x4*)(ap + i0);
        u32x4 A1 = *(const u32x4*)(ap + (i0 ^ 8));
        i32x4 ah, al; unpack_hl(A0, A1, ah, al);
        const int wc = s ^ (m16 & 7);
        i32x4 bq = *(const i32x4*)(w0s + m16 * 256 + (wc << 4));
        ph = mfma_i8_16(ah, bq, ph);
        p1 = mfma_i8_16(al, bq, p1);
      }
      #pragma unroll
      for (int r = 0; r < 4; ++r) {
        float v = clamp01(b0v + (float)((ph[r] << 8) + p1[r]) * 0x1p-25f);
        int row = 16 * w + g4 * 4 + r;
        if (m16 < 10) {
          s0n[row * S0_STRIDE + m16] = enc_q(v);
          if (last) out0[(rb + row) * 10 + m16] = v;
        }
      }
    }

    __syncthreads();   // next-state buffers fully written; old fully read
    u16* tp;
    tp = s1c; s1c = s1n; s1n = tp;
    tp = s2c; s2c = s2n; s2n = tp;
    tp = s0c; s0c = s0n; s0n = tp;
  }
}

// ---------------- launcher ---------------------------------------------------
extern "C" void kernel_launch(void* const* d_in, const int* in_sizes, int n_in,
                              void* d_out, int out_size, void* d_ws, size_t ws_size,
                              hipStream_t stream) {
  const float* data = (const float*)d_in[0];
  const float* s0g  = (const float*)d_in[1];
  const float* s1g  = (const float*)d_in[2];
  const float* s2g  = (const float*)d_in[3];
  const float* W0   = (const float*)d_in[4];
  const float* b0   = (const float*)d_in[5];
  const float* W1   = (const float*)d_in[6];
  const float* W2   = (const float*)d_in[7];
  const float* b2   = (const float*)d_in[8];
  const float* W3   = (const float*)d_in[9];
  const float* W4   = (const float*)d_in[10];
  const float* b4   = (const float*)d_in[11];
  const int*   Tp   = (const int*)d_in[12];

  char* ws = (char*)d_ws;
  float* drive = (float*)ws;                                  // 16 MB
  size_t off = 16777216;
  signed char* w2q = (signed char*)(ws + off); off += 65536;
  signed char* w3q = (signed char*)(ws + off); off += 65536;
  signed char* w0q = (signed char*)(ws + off); off += 4096;
  signed char* w1q = (signed char*)(ws + off); off += 8192;
  u16* w4h = (u16*)(ws + off); off += 401408;
  u16* w4l = (u16*)(ws + off); off += 401408;
  float* b0p = (float*)(ws + off); off += 64;

  float* out0 = (float*)d_out;
  float* out1 = out0 + 16384 * 10;
  float* out2 = out1 + 16384 * 256;

  hipFuncSetAttribute((const void*)k_main,
                      hipFuncAttributeMaxDynamicSharedMemorySize, 74752);

  k_prep_w<<<784, 256, 0, stream>>>(W2, W3, W4, W0, w2q, w3q, w0q, w4h, w4l);
  k_prep_small<<<33, 256, 0, stream>>>(W1, b0, w1q, b0p);
  k_drive<<<256, 256, 0, stream>>>(data, w4h, w4l, b4, drive);
  k_main<<<512, 512, 74752, stream>>>(s0g, s1g, s2g, b2, Tp,
      w2q, w3q, w0q, w1q, b0p, drive, out0, out1, out2);
}